// Round 2
// baseline (9921.103 us; speedup 1.0000x reference)
//
#include <hip/hip_runtime.h>

#define T_STEPS 512
#define B 64
#define DIN 1024
#define DH 1024
#define EPS 1e-5f

// ---------------------------------------------------------------------------
// Kernel A: Xp = X @ W_x + bias      (M=T*B=32768, K=DIN=1024, N=DH=1024)
// 64x64 block tile, 256 threads, 4x4 micro-tile, K-chunk 32. fp32 VALU.
// Writes into the second output copy region (used as Xp scratch, later
// overwritten by the final outputs).
// ---------------------------------------------------------------------------
__global__ __launch_bounds__(256) void gemm_xp(
    const float* __restrict__ X, const float* __restrict__ Wx,
    const float* __restrict__ bias, float* __restrict__ Xp)
{
    // stride 68 floats: keeps float4 LDS accesses 16B-aligned (68 % 4 == 0)
    __shared__ float As[32][68];   // A tile, transposed: As[k][m]
    __shared__ float Bs[32][68];   // B tile: Bs[k][n]

    const int m0 = blockIdx.y * 64;
    const int n0 = blockIdx.x * 64;
    const int tid = threadIdx.x;
    const int tx = tid & 15;       // micro col group
    const int ty = tid >> 4;       // micro row group

    // load mapping
    const int ar = tid >> 2;           // A tile row   0..63
    const int ak = (tid & 3) * 8;      // A tile k off (8 floats)
    const int bk = tid >> 3;           // B tile k row 0..31
    const int bn = (tid & 7) * 8;      // B tile n off (8 floats)

    float acc[4][4] = {};

    for (int k0 = 0; k0 < DIN; k0 += 32) {
        const float4 a0 = *(const float4*)&X[(size_t)(m0 + ar) * DIN + k0 + ak];
        const float4 a1 = *(const float4*)&X[(size_t)(m0 + ar) * DIN + k0 + ak + 4];
        const float4 b0 = *(const float4*)&Wx[(size_t)(k0 + bk) * DH + n0 + bn];
        const float4 b1 = *(const float4*)&Wx[(size_t)(k0 + bk) * DH + n0 + bn + 4];

        __syncthreads();   // previous iteration done reading LDS
        As[ak + 0][ar] = a0.x; As[ak + 1][ar] = a0.y;
        As[ak + 2][ar] = a0.z; As[ak + 3][ar] = a0.w;
        As[ak + 4][ar] = a1.x; As[ak + 5][ar] = a1.y;
        As[ak + 6][ar] = a1.z; As[ak + 7][ar] = a1.w;
        *(float4*)&Bs[bk][bn]     = b0;
        *(float4*)&Bs[bk][bn + 4] = b1;
        __syncthreads();

        #pragma unroll
        for (int kk = 0; kk < 32; ++kk) {
            const float4 av = *(const float4*)&As[kk][ty * 4];
            const float4 bv = *(const float4*)&Bs[kk][tx * 4];
            const float a[4] = {av.x, av.y, av.z, av.w};
            const float b[4] = {bv.x, bv.y, bv.z, bv.w};
            #pragma unroll
            for (int i = 0; i < 4; ++i)
                #pragma unroll
                for (int j = 0; j < 4; ++j)
                    acc[i][j] = fmaf(a[i], b[j], acc[i][j]);
        }
    }

    const float4 bv = *(const float4*)&bias[n0 + tx * 4];
    #pragma unroll
    for (int i = 0; i < 4; ++i) {
        float4 c;
        c.x = acc[i][0] + bv.x;
        c.y = acc[i][1] + bv.y;
        c.z = acc[i][2] + bv.z;
        c.w = acc[i][3] + bv.w;
        *(float4*)&Xp[(size_t)(m0 + ty * 4 + i) * DH + n0 + tx * 4] = c;
    }
}

// ---------------------------------------------------------------------------
// transpose initial state [B][DH] -> sT [DH][B]  (grid-stride, robust)
// ---------------------------------------------------------------------------
__global__ __launch_bounds__(256) void transpose_state(
    const float* __restrict__ st, float* __restrict__ sT)
{
    for (int g = blockIdx.x * 256 + threadIdx.x; g < DH * B; g += gridDim.x * 256) {
        const int j = g >> 6;
        const int b = g & 63;
        sT[g] = st[b * DH + j];
    }
}

// ---------------------------------------------------------------------------
// One recurrence step:
//   h = tanh(Xp[t] + s_prev @ W_h);  s = BN_batch(h);  write s to out1/out2,
//   and transposed into sT_next (coalesced state for the next step).
// Grid: 256 blocks (4 columns each) x 512 threads (8 waves, 8-way K split).
// s_prev is held transposed, so the GEMM A-read is coalesced (lane = batch).
// W_h rows are wave-uniform -> scalar loads (s_load_dwordx4).
// Xp aliases out2 (read slice t, then overwrite slice t) -> no __restrict__.
// ---------------------------------------------------------------------------
__global__ __launch_bounds__(512) void rnn_step(
    const int t,
    const float* __restrict__ sT_prev, float* __restrict__ sT_next,
    const float* __restrict__ Wh,
    const float* Xp, float* out1, float* out2)
{
    __shared__ float part[8][B][4];   // per-wave partial sums (8 KB)
    __shared__ float sL[B][4];        // normalized outputs for write phase

    const int tid  = threadIdx.x;
    const int lane = tid & 63;                                   // batch index
    const int w    = __builtin_amdgcn_readfirstlane(tid >> 6);   // wave id 0..7 (SGPR)
    const int j0   = blockIdx.x * 4;                             // column base

    // ---- phase 1: partial GEMM over k in [w*128, w*128+128) ----
    float acc0 = 0.f, acc1 = 0.f, acc2 = 0.f, acc3 = 0.f;
    const int kbase = w * 128;
    #pragma unroll 16
    for (int kk = 0; kk < 128; ++kk) {
        const int k = kbase + kk;
        const float v = sT_prev[k * B + lane];                      // coalesced
        const float4 wv = *(const float4*)&Wh[(size_t)k * DH + j0]; // uniform -> s_load
        acc0 = fmaf(wv.x, v, acc0);
        acc1 = fmaf(wv.y, v, acc1);
        acc2 = fmaf(wv.z, v, acc2);
        acc3 = fmaf(wv.w, v, acc3);
    }
    *(float4*)&part[w][lane][0] = make_float4(acc0, acc1, acc2, acc3);
    __syncthreads();

    // ---- phase 2: reduce + tanh + batch-norm (threads 0..255) ----
    if (tid < 256) {
        const int c = tid >> 6;   // column 0..3 == wave id (uniform per wave)
        const int b = lane;
        float h = Xp[(size_t)(t * B + b) * DH + j0 + c];
        #pragma unroll
        for (int ww = 0; ww < 8; ++ww) h += part[ww][b][c];
        h = tanhf(h);

        float sum = h, sq = h * h;
        #pragma unroll
        for (int off = 32; off > 0; off >>= 1) {
            sum += __shfl_xor(sum, off);
            sq  += __shfl_xor(sq, off);
        }
        const float mu  = sum * (1.0f / 64.0f);
        const float var = sq * (1.0f / 64.0f) - mu * mu;   // biased, matches jnp.var
        const float s = (h - mu) * (1.0f / sqrtf(var + EPS));
        sL[b][c] = s;
    }
    __syncthreads();

    // ---- phase 3: writes (threads 0..63) ----
    if (tid < B) {
        const int b = tid;
        const float4 sv = *(const float4*)&sL[b][0];
        const size_t o = (size_t)(t * B + b) * DH + j0;
        *(float4*)&out1[o] = sv;
        *(float4*)&out2[o] = sv;   // overwrites this step's Xp slice (already consumed)
        sT_next[(j0 + 0) * B + b] = sv.x;
        sT_next[(j0 + 1) * B + b] = sv.y;
        sT_next[(j0 + 2) * B + b] = sv.z;
        sT_next[(j0 + 3) * B + b] = sv.w;
    }
}

// ---------------------------------------------------------------------------
extern "C" void kernel_launch(void* const* d_in, const int* in_sizes, int n_in,
                              void* d_out, int out_size, void* d_ws, size_t ws_size,
                              hipStream_t stream)
{
    const float* X    = (const float*)d_in[0];   // [T,B,DIN]
    const float* st   = (const float*)d_in[1];   // [1,B,DH]
    const float* Wx   = (const float*)d_in[2];   // [DIN,DH]
    const float* Wh   = (const float*)d_in[3];   // [DH,DH]
    const float* bias = (const float*)d_in[4];   // [DH]

    float* out1 = (float*)d_out;
    float* out2 = out1 + (size_t)T_STEPS * B * DH;   // second copy; doubles as Xp scratch

    // 2 x 256 KB state ping-pong in workspace (ws requirement: 512 KB)
    float* sT0 = (float*)d_ws;
    float* sT1 = sT0 + DH * B;

    // Xp = X @ Wx + b  -> staged in out2 region
    gemm_xp<<<dim3(DH / 64, (T_STEPS * B) / 64), 256, 0, stream>>>(X, Wx, bias, out2);

    // s_T(0) = state^T
    transpose_state<<<(DH * B) / 256, 256, 0, stream>>>(st, sT0);

    for (int t = 0; t < T_STEPS; ++t) {
        float* sp = (t & 1) ? sT1 : sT0;
        float* sn = (t & 1) ? sT0 : sT1;
        rnn_step<<<DH / 4, 512, 0, stream>>>(t, sp, sn, Wh, out2, out1, out2);
    }
}